// Round 7
// baseline (3655.534 us; speedup 1.0000x reference)
//
#include <hip/hip_runtime.h>
#include <hip/hip_bf16.h>
#include <hip/hip_fp16.h>

#define HD 2
#define LAYERS 4
#define RELS 16
#define BASES 8

#define TSH    14                 // dst tile shift: 16384 nodes per tile
#define TILEN  (1 << TSH)
#define SBH    11                 // src block shift: 2048 nodes (8KB x window)
#define SRCB_BITS 9               // 512 src blocks
#define KEYS   32768              // (dst>>TSH)<<9 | (src>>SBH); N<=2^20
#define SBLK   192                // sort chunk blocks
#define TPB    256
#define ETPB   1024               // edge kernel threads (16 waves)

static const int KEYS_LDS_BYTES = KEYS * 4;           // 128 KB (hist/scatter)
static const int EDGE_LDS_BYTES = 2 * TILEN * 4;      // 128 KB (acc0+acc1)

// ============================ common ============================

// W[l][r][i][o] = sum_b comp[l,r,b] * V[l,b,i,o]; zero dot accumulator.
__global__ void prep_kernel(const float* __restrict__ V, const float* __restrict__ comp,
                            float* __restrict__ W, float* __restrict__ acc) {
    int idx = threadIdx.x;            // 0..255 = l*64 + r*4 + io
    if (idx < LAYERS * RELS * 4) {
        int l  = idx >> 6;
        int r  = (idx >> 2) & (RELS - 1);
        int io = idx & 3;
        float s = 0.f;
        for (int b = 0; b < BASES; ++b)
            s += comp[(l * RELS + r) * BASES + b] * V[(l * BASES + b) * 4 + io];
        W[idx] = s;
    }
    if (idx == 0) *acc = 0.f;
}

__global__ void finalize_kernel(const float* __restrict__ acc,
                                const float* __restrict__ b_mlp,
                                float* __restrict__ out) {
    float v = *acc + b_mlp[0];
    out[0] = 1.f / (1.f + expf(-v));
}

// features f32 -> half2 (4B/node): gather working set 4MB = one XCD L2.
__global__ __launch_bounds__(TPB) void f2h_kernel(const float2* __restrict__ f,
                                                  __half2* __restrict__ h, int N) {
    int i = blockIdx.x * TPB + threadIdx.x;
    int stride = gridDim.x * TPB;
    for (; i < N; i += stride)
        h[i] = __float22half2_rn(f[i]);
}

// ============================ sort path ============================
// key = (dst>>TSH)<<SRCB_BITS | (src>>SBH): groups edges by 16K-node dst tile,
// then by 2048-node src block -> the edge kernel's x gathers walk 8KB windows
// (L1-resident) instead of random 4MB.

// S1: per-chunk histogram of keys.
__global__ __launch_bounds__(TPB) void hist_kernel(const int* __restrict__ src,
                                                   const int* __restrict__ dst,
                                                   unsigned* __restrict__ blockhist,
                                                   int E, int per) {
    extern __shared__ unsigned hist[];   // KEYS
    for (int i = threadIdx.x; i < KEYS; i += TPB) hist[i] = 0u;
    __syncthreads();
    int blk = blockIdx.x;
    int e0 = blk * per;              // multiple of 4
    int e1 = min(e0 + per, E);
    const int4* src4 = (const int4*)src;
    const int4* dst4 = (const int4*)dst;
    int g0 = e0 >> 2, g1 = e1 >> 2;
    for (int g = g0 + threadIdx.x; g < g1; g += TPB) {
        int4 s = src4[g];
        int4 d = dst4[g];
        atomicAdd(&hist[((((unsigned)d.x) >> TSH) << SRCB_BITS) | (((unsigned)s.x) >> SBH)], 1u);
        atomicAdd(&hist[((((unsigned)d.y) >> TSH) << SRCB_BITS) | (((unsigned)s.y) >> SBH)], 1u);
        atomicAdd(&hist[((((unsigned)d.z) >> TSH) << SRCB_BITS) | (((unsigned)s.z) >> SBH)], 1u);
        atomicAdd(&hist[((((unsigned)d.w) >> TSH) << SRCB_BITS) | (((unsigned)s.w) >> SBH)], 1u);
    }
    for (int e = (g1 << 2) + threadIdx.x; e < e1; e += TPB)   // tail
        atomicAdd(&hist[((((unsigned)dst[e]) >> TSH) << SRCB_BITS) | (((unsigned)src[e]) >> SBH)], 1u);
    __syncthreads();
    for (int i = threadIdx.x; i < KEYS; i += TPB)
        blockhist[(size_t)blk * KEYS + i] = hist[i];
}

// S2a: per-key column exclusive scan over SBLK chunks (in place); totals[key].
// One wave per key; 3 chunks per thread (64*3 = 192 = SBLK).
__global__ __launch_bounds__(64) void colscan_kernel(unsigned* __restrict__ blockhist,
                                                     unsigned* __restrict__ totals) {
    int key = blockIdx.x;
    int t = threadIdx.x;              // 0..63, single wave
    unsigned v0 = blockhist[(size_t)(3 * t)     * KEYS + key];
    unsigned v1 = blockhist[(size_t)(3 * t + 1) * KEYS + key];
    unsigned v2 = blockhist[(size_t)(3 * t + 2) * KEYS + key];
    unsigned run = v0 + v1 + v2;
    unsigned v = run;
    for (int o = 1; o < 64; o <<= 1) {
        unsigned u = __shfl_up(v, o, 64);
        if (t >= o) v += u;
    }
    unsigned excl = v - run;
    blockhist[(size_t)(3 * t)     * KEYS + key] = excl;
    blockhist[(size_t)(3 * t + 1) * KEYS + key] = excl + v0;
    blockhist[(size_t)(3 * t + 2) * KEYS + key] = excl + v0 + v1;
    if (t == 63) totals[key] = v;
}

// S2b: exclusive scan of KEYS totals -> base[KEYS+1].  32 bins per thread.
__global__ __launch_bounds__(ETPB) void scan_kernel(const unsigned* __restrict__ totals,
                                                    unsigned* __restrict__ base) {
    __shared__ unsigned wpart[ETPB / 64];
    int t = threadIdx.x;
    unsigned run = 0;
    for (int k = 0; k < 32; ++k) run += totals[t * 32 + k];
    unsigned lane = t & 63, wv = t >> 6;
    unsigned v = run;
    for (int o = 1; o < 64; o <<= 1) {
        unsigned u = __shfl_up(v, o, 64);
        if (lane >= (unsigned)o) v += u;
    }
    if (lane == 63) wpart[wv] = v;
    __syncthreads();
    unsigned wbase = 0;
    for (int w = 0; w < (int)(ETPB / 64); ++w) if ((unsigned)w < wv) wbase += wpart[w];
    unsigned e = wbase + v - run;
    for (int k = 0; k < 32; ++k) {
        base[t * 32 + k] = e;
        e += totals[t * 32 + k];
    }
    if (t == ETPB - 1) base[KEYS] = e;   // == E
}

// S3: scatter edges into key order (atomic LDS cursors; writes scattered but
// each key run fills contiguously -> acceptable amp, proven ~230us shape).
// record: w0 = src(0:19) | typ(20:23) | doffL8(24:31); w1 = doffH6(0:5) | f16(norm)(16:31)
__global__ __launch_bounds__(TPB) void scatter_kernel(const int* __restrict__ src,
                                                      const int* __restrict__ dst,
                                                      const int* __restrict__ typ,
                                                      const float* __restrict__ norm,
                                                      const unsigned* __restrict__ blockhist,
                                                      const unsigned* __restrict__ base,
                                                      uint2* __restrict__ packed,
                                                      int E, int per) {
    extern __shared__ unsigned cnt[];   // KEYS
    int blk = blockIdx.x;
    for (int i = threadIdx.x; i < KEYS; i += TPB)
        cnt[i] = blockhist[(size_t)blk * KEYS + i] + base[i];
    __syncthreads();
    int e0 = blk * per;
    int e1 = min(e0 + per, E);
    const int4*   src4 = (const int4*)src;
    const int4*   dst4 = (const int4*)dst;
    const int4*   typ4 = (const int4*)typ;
    const float4* nrm4 = (const float4*)norm;
    int g0 = e0 >> 2, g1 = e1 >> 2;

#define PUT(SS, DD, TT, NN)                                                        \
    {                                                                              \
        unsigned _s = (unsigned)(SS);                                              \
        unsigned _d = (unsigned)(DD);                                              \
        unsigned _key = ((_d >> TSH) << SRCB_BITS) | (_s >> SBH);                  \
        unsigned _pos = atomicAdd(&cnt[_key], 1u);                                 \
        unsigned _doff = _d & (TILEN - 1u);                                        \
        unsigned _w0 = _s | (((unsigned)(TT)) << 20) | ((_doff & 0xFFu) << 24);    \
        unsigned _w1 = (_doff >> 8) |                                              \
                       ((unsigned)__half_as_ushort(__float2half_rn(NN)) << 16);    \
        packed[_pos] = make_uint2(_w0, _w1);                                       \
    }

    for (int g = g0 + threadIdx.x; g < g1; g += TPB) {
        int4 s = src4[g];
        int4 d = dst4[g];
        int4 t = typ4[g];
        float4 nm = nrm4[g];
        PUT(s.x, d.x, t.x, nm.x)
        PUT(s.y, d.y, t.y, nm.y)
        PUT(s.z, d.z, t.z, nm.z)
        PUT(s.w, d.w, t.w, nm.w)
    }
    for (int e = (g1 << 2) + threadIdx.x; e < e1; e += TPB)   // tail
        PUT(src[e], dst[e], typ[e], norm[e])
#undef PUT
}

// Edge pass: one block (16 waves) per 16K-node dst tile. Streams the tile's
// edge range (sorted by src block -> x gathers hit 8KB L1-resident windows),
// accumulates into a 128KB LDS f32 accumulator via LDS atomics, then runs the
// fused epilogue (bias, relu, skip, half2 store, w_mlp dot partial).
__global__ __launch_bounds__(ETPB) void edge_tile_kernel(
    const unsigned long long* __restrict__ rec8,  // packed, key order
    const unsigned* __restrict__ base,            // [KEYS+1]
    const __half2* __restrict__ xh,               // gather source [N], 4MB
    const float* __restrict__ Wl,                 // [64] this layer
    const float* __restrict__ bias2,              // [2]
    const __half2* __restrict__ skiph,            // nullable
    __half2* __restrict__ outh,                   // nullable
    const float2* __restrict__ w2,                // nullable (w_mlp as float2[N])
    float* __restrict__ acc,                      // dot accumulator
    int N, int do_relu)
{
    extern __shared__ float dsm[];
    float* acc0 = dsm;                 // TILEN
    float* acc1 = dsm + TILEN;         // TILEN
    __shared__ float sW[64];
    __shared__ float wred[ETPB / 64];

    int t = threadIdx.x;
    for (int i = t; i < TILEN; i += ETPB) { acc0[i] = 0.f; acc1[i] = 0.f; }
    if (t < 64) sW[t] = Wl[t];
    __syncthreads();

    int tile = blockIdx.x;
    unsigned e0 = base[tile << SRCB_BITS];
    unsigned e1 = base[min((tile + 1) << SRCB_BITS, KEYS)];

    for (unsigned e = e0 + t; e < e1; e += ETPB) {
        unsigned long long q = __builtin_nontemporal_load(&rec8[e]);
        unsigned w0 = (unsigned)q;
        unsigned w1 = (unsigned)(q >> 32);
        unsigned src  = w0 & 0xFFFFFu;
        int      wb   = (int)((w0 >> 20) & 15u) << 2;
        unsigned doff = (w0 >> 24) | ((w1 & 0x3Fu) << 8);
        float    nm   = __half2float(__ushort_as_half((unsigned short)(w1 >> 16)));
        __half2  hv   = xh[src];
        float x0 = __low2float(hv), x1 = __high2float(hv);
        float m0 = (x0 * sW[wb + 0] + x1 * sW[wb + 2]) * nm;
        float m1 = (x0 * sW[wb + 1] + x1 * sW[wb + 3]) * nm;
        atomicAdd(&acc0[doff], m0);
        atomicAdd(&acc1[doff], m1);
    }
    __syncthreads();

    float b0 = bias2[0], b1 = bias2[1];
    int nodeBase = tile << TSH;
    float part = 0.f;
    for (int k = 0; k < TILEN / ETPB; ++k) {
        int i = k * ETPB + t;
        int node = nodeBase + i;
        if (node < N) {
            float v0 = acc0[i] + b0;
            float v1 = acc1[i] + b1;
            if (do_relu) { v0 = fmaxf(v0, 0.f); v1 = fmaxf(v1, 0.f); }
            if (skiph) {
                __half2 sv = skiph[node];
                v0 += __low2float(sv); v1 += __high2float(sv);
            }
            if (outh) outh[node] = __float22half2_rn(make_float2(v0, v1));
            if (w2)   { float2 wv = w2[node]; part += v0 * wv.x + v1 * wv.y; }
        }
    }
    if (w2) {
        for (int o = 32; o > 0; o >>= 1) part += __shfl_down(part, o, 64);
        if ((t & 63) == 0) wred[t >> 6] = part;
        __syncthreads();
        if (t == 0) {
            float s = 0.f;
            for (int w = 0; w < (int)(ETPB / 64); ++w) s += wred[w];
            atomicAdd(acc, s);
        }
    }
}

// ============================ fallback path (round-1, known-good) ============================

__global__ void zero_kernel(float4* __restrict__ p, int n4) {
    int i = blockIdx.x * blockDim.x + threadIdx.x;
    int stride = gridDim.x * blockDim.x;
    for (; i < n4; i += stride) p[i] = make_float4(0.f, 0.f, 0.f, 0.f);
}

__global__ __launch_bounds__(256) void edge_kernel(
    const float* __restrict__ x, const int* __restrict__ src,
    const int* __restrict__ dst, const int* __restrict__ typ,
    const float* __restrict__ norm, const float* __restrict__ Wl,
    float* __restrict__ h, int E)
{
    __shared__ float sW[64];
    if (threadIdx.x < 64) sW[threadIdx.x] = Wl[threadIdx.x];
    __syncthreads();
    const float2* __restrict__ x2 = (const float2*)x;
    int tid = blockIdx.x * blockDim.x + threadIdx.x;
    int stride = gridDim.x * blockDim.x;
    for (int e = tid; e < E; e += stride) {
        int s = src[e], d = dst[e], t = typ[e];
        float nm = norm[e];
        float2 xv = x2[s];
        int wb = t << 2;
        float m0 = (xv.x * sW[wb + 0] + xv.y * sW[wb + 2]) * nm;
        float m1 = (xv.x * sW[wb + 1] + xv.y * sW[wb + 3]) * nm;
        atomicAdd(&h[2 * (size_t)d],     m0);
        atomicAdd(&h[2 * (size_t)d + 1], m1);
    }
}

__global__ void node_kernel(const float* __restrict__ h, const float* __restrict__ bias_l,
                            const float* __restrict__ skip, float* __restrict__ xout,
                            int N, int do_relu)
{
    float b0 = bias_l[0], b1 = bias_l[1];
    const float2* __restrict__ h2 = (const float2*)h;
    const float2* __restrict__ s2 = (const float2*)skip;
    float2* __restrict__ o2 = (float2*)xout;
    int i = blockIdx.x * blockDim.x + threadIdx.x;
    int stride = gridDim.x * blockDim.x;
    for (; i < N; i += stride) {
        float2 v = h2[i];
        v.x += b0; v.y += b1;
        if (do_relu) { v.x = fmaxf(v.x, 0.f); v.y = fmaxf(v.y, 0.f); }
        if (skip) { float2 sv = s2[i]; v.x += sv.x; v.y += sv.y; }
        o2[i] = v;
    }
}

__global__ __launch_bounds__(256) void dot_kernel(const float* __restrict__ a,
                                                  const float* __restrict__ b,
                                                  float* __restrict__ acc, int n)
{
    int i = blockIdx.x * blockDim.x + threadIdx.x;
    int stride = gridDim.x * blockDim.x;
    float s = 0.f;
    int n4 = n >> 2;
    const float4* __restrict__ a4 = (const float4*)a;
    const float4* __restrict__ b4 = (const float4*)b;
    for (int g = i; g < n4; g += stride) {
        float4 av = a4[g], bv = b4[g];
        s += av.x * bv.x + av.y * bv.y + av.z * bv.z + av.w * bv.w;
    }
    for (int e = (n4 << 2) + i; e < n; e += stride) s += a[e] * b[e];
    for (int off = 32; off > 0; off >>= 1) s += __shfl_down(s, off, 64);
    __shared__ float wsum[4];
    int lane = threadIdx.x & 63, wv = threadIdx.x >> 6;
    if (lane == 0) wsum[wv] = s;
    __syncthreads();
    if (threadIdx.x == 0) atomicAdd(acc, wsum[0] + wsum[1] + wsum[2] + wsum[3]);
}

// ============================ launch ============================

static inline size_t align256(size_t x) { return (x + 255) & ~(size_t)255; }

extern "C" void kernel_launch(void* const* d_in, const int* in_sizes, int n_in,
                              void* d_out, int out_size, void* d_ws, size_t ws_size,
                              hipStream_t stream) {
    const float* features = (const float*)d_in[0];   // [N*2]
    const float* norm     = (const float*)d_in[1];   // [E]
    const float* V        = (const float*)d_in[2];   // [L,B,2,2]
    const float* comp     = (const float*)d_in[3];   // [L,R,B]
    const float* bias     = (const float*)d_in[4];   // [L,2]
    const float* w_mlp    = (const float*)d_in[5];   // [N*2]
    const float* b_mlp    = (const float*)d_in[6];   // [1]
    const int*   esrc     = (const int*)d_in[7];
    const int*   edst     = (const int*)d_in[8];
    const int*   etyp     = (const int*)d_in[9];

    int NH = in_sizes[0];
    int N  = NH / 2;
    int E  = in_sizes[7];

    char* ws = (char*)d_ws;
    size_t oW    = 0;                                        // [256] f32
    size_t oAcc  = align256(oW + 1024);
    size_t oBase = align256(oAcc + 4);                       // u32 [KEYS+1]
    size_t oTot  = align256(oBase + (size_t)(KEYS + 1) * 4); // u32 [KEYS]
    size_t oFH   = align256(oTot + (size_t)KEYS * 4);        // half2 features [N]
    size_t oAH   = align256(oFH + (size_t)N * 4);
    size_t oBH   = align256(oAH + (size_t)N * 4);
    size_t oCH   = align256(oBH + (size_t)N * 4);
    size_t oHist = align256(oCH + (size_t)N * 4);            // u32 [SBLK*KEYS] = 24MB
    size_t oPack = align256(oHist + (size_t)SBLK * KEYS * 4);// uint2 [E] = 128MB
    size_t REQ   = oPack + (size_t)E * 8;                    // ~168.5MB

    // fallback f32 scratch overlays the sort-path big arrays
    float* A = (float*)(ws + oFH);      // 8MB: spans FH+AH
    float* B = (float*)(ws + oBH);      // 8MB: spans BH+CH
    float* C = (float*)(ws + oPack);    // 8MB: start of pack region

    float* W   = (float*)(ws + oW);
    float* acc = (float*)(ws + oAcc);

    prep_kernel<<<1, 256, 0, stream>>>(V, comp, W, acc);

    if (ws_size >= REQ && N <= (1 << 20)) {
        __half2* FH = (__half2*)(ws + oFH);
        __half2* AH = (__half2*)(ws + oAH);
        __half2* BH = (__half2*)(ws + oBH);
        __half2* CH = (__half2*)(ws + oCH);
        unsigned* base      = (unsigned*)(ws + oBase);
        unsigned* totals    = (unsigned*)(ws + oTot);
        unsigned* blockhist = (unsigned*)(ws + oHist);
        uint2*    packed    = (uint2*)(ws + oPack);
        unsigned long long* packed8 = (unsigned long long*)packed;

        int per = (((E + SBLK - 1) / SBLK) + 3) & ~3;   // multiple of 4
        int ntiles = (N + TILEN - 1) / TILEN;           // 62 for N=1M

        static bool attr_done = false;
        if (!attr_done) {
            (void)hipFuncSetAttribute((const void*)hist_kernel,
                                      hipFuncAttributeMaxDynamicSharedMemorySize,
                                      KEYS_LDS_BYTES);
            (void)hipFuncSetAttribute((const void*)scatter_kernel,
                                      hipFuncAttributeMaxDynamicSharedMemorySize,
                                      KEYS_LDS_BYTES);
            (void)hipFuncSetAttribute((const void*)edge_tile_kernel,
                                      hipFuncAttributeMaxDynamicSharedMemorySize,
                                      EDGE_LDS_BYTES);
            attr_done = true;
        }

        int cb = min((N + TPB - 1) / TPB, 2048);
        f2h_kernel    <<<cb,   TPB, 0, stream>>>((const float2*)features, FH, N);
        hist_kernel   <<<SBLK, TPB, KEYS_LDS_BYTES, stream>>>(esrc, edst, blockhist, E, per);
        colscan_kernel<<<KEYS, 64,  0, stream>>>(blockhist, totals);
        scan_kernel   <<<1,    ETPB, 0, stream>>>(totals, base);
        scatter_kernel<<<SBLK, TPB, KEYS_LDS_BYTES, stream>>>(
            esrc, edst, etyp, norm, blockhist, base, packed, E, per);

        const float2* w2 = (const float2*)w_mlp;

        // L0: AH = relu(h0 + b0)
        edge_tile_kernel<<<ntiles, ETPB, EDGE_LDS_BYTES, stream>>>(packed8, base, FH, W + 0,
            bias + 0, nullptr, AH, nullptr, acc, N, 1);
        // L1: BH = relu(h1 + b1) + features
        edge_tile_kernel<<<ntiles, ETPB, EDGE_LDS_BYTES, stream>>>(packed8, base, AH, W + 64,
            bias + 2, FH, BH, nullptr, acc, N, 1);
        // L2: CH = relu(h2 + b2)
        edge_tile_kernel<<<ntiles, ETPB, EDGE_LDS_BYTES, stream>>>(packed8, base, BH, W + 128,
            bias + 4, nullptr, CH, nullptr, acc, N, 1);
        // L3: x4 = (h3 + b3) + B, fused dot with w_mlp (x4 not stored)
        edge_tile_kernel<<<ntiles, ETPB, EDGE_LDS_BYTES, stream>>>(packed8, base, CH, W + 192,
            bias + 6, BH, nullptr, w2, acc, N, 0);
    } else {
        // fallback: round-1 atomic path (f32 throughout)
        int zb = (NH / 4 + 255) / 256;
        int eb = (E / 4 + 255) / 256;
        int nb = (N + 255) / 256;
        int db = (NH / 4 + 255) / 256;

        zero_kernel<<<zb, 256, 0, stream>>>((float4*)A, NH / 4);
        edge_kernel<<<eb, 256, 0, stream>>>(features, esrc, edst, etyp, norm, W + 0, A, E);
        node_kernel<<<nb, 256, 0, stream>>>(A, bias + 0, nullptr, A, N, 1);

        zero_kernel<<<zb, 256, 0, stream>>>((float4*)B, NH / 4);
        edge_kernel<<<eb, 256, 0, stream>>>(A, esrc, edst, etyp, norm, W + 64, B, E);
        node_kernel<<<nb, 256, 0, stream>>>(B, bias + 2, features, B, N, 1);

        zero_kernel<<<zb, 256, 0, stream>>>((float4*)C, NH / 4);
        edge_kernel<<<eb, 256, 0, stream>>>(B, esrc, edst, etyp, norm, W + 128, C, E);
        node_kernel<<<nb, 256, 0, stream>>>(C, bias + 4, nullptr, C, N, 1);

        zero_kernel<<<zb, 256, 0, stream>>>((float4*)A, NH / 4);
        edge_kernel<<<eb, 256, 0, stream>>>(C, esrc, edst, etyp, norm, W + 192, A, E);
        node_kernel<<<nb, 256, 0, stream>>>(A, bias + 6, B, A, N, 0);

        dot_kernel<<<db, 256, 0, stream>>>(A, w_mlp, acc, NH);
    }

    finalize_kernel<<<1, 1, 0, stream>>>(acc, b_mlp, (float*)d_out);
}

// Round 8
// 2264.759 us; speedup vs baseline: 1.6141x; 1.6141x over previous
//
#include <hip/hip_runtime.h>
#include <hip/hip_bf16.h>
#include <hip/hip_fp16.h>

#define HD 2
#define LAYERS 4
#define RELS 16
#define BASES 8

#define TSH    14                 // dst tile shift: 16384 nodes per tile
#define TILEN  (1 << TSH)
#define SBH    12                 // src block shift: 4096 nodes (16KB LDS window)
#define SRCWIN (1 << SBH)
#define SRCB_BITS 8               // 256 src blocks
#define KEYS   16384              // (dst>>TSH)<<8 | (src>>SBH); N<=2^20
#define SPLIT  8                  // blocks per dst tile in edge pass
#define RUNS_PER_BLOCK ((1 << SRCB_BITS) / SPLIT)   // 32
#define SBLK   192                // sort chunk blocks
#define TPB    256
#define ETPB   1024               // edge kernel threads (16 waves)

static const int KEYS_LDS_BYTES = KEYS * 4;                       // 64 KB
static const int EDGE_LDS_BYTES = 2 * TILEN * 4 + SRCWIN * 4;     // 144 KB

// ============================ common ============================

// W[l][r][i][o] = sum_b comp[l,r,b] * V[l,b,i,o]; zero dot accumulator.
__global__ void prep_kernel(const float* __restrict__ V, const float* __restrict__ comp,
                            float* __restrict__ W, float* __restrict__ acc) {
    int idx = threadIdx.x;            // 0..255 = l*64 + r*4 + io
    if (idx < LAYERS * RELS * 4) {
        int l  = idx >> 6;
        int r  = (idx >> 2) & (RELS - 1);
        int io = idx & 3;
        float s = 0.f;
        for (int b = 0; b < BASES; ++b)
            s += comp[(l * RELS + r) * BASES + b] * V[(l * BASES + b) * 4 + io];
        W[idx] = s;
    }
    if (idx == 0) *acc = 0.f;
}

__global__ void finalize_kernel(const float* __restrict__ acc,
                                const float* __restrict__ b_mlp,
                                float* __restrict__ out) {
    float v = *acc + b_mlp[0];
    out[0] = 1.f / (1.f + expf(-v));
}

// features f32 -> half2 (4B/node).
__global__ __launch_bounds__(TPB) void f2h_kernel(const float2* __restrict__ f,
                                                  __half2* __restrict__ h, int N) {
    int i = blockIdx.x * TPB + threadIdx.x;
    int stride = gridDim.x * TPB;
    for (; i < N; i += stride)
        h[i] = __float22half2_rn(f[i]);
}

__global__ void zero_kernel(float4* __restrict__ p, int n4) {
    int i = blockIdx.x * blockDim.x + threadIdx.x;
    int stride = gridDim.x * blockDim.x;
    for (; i < n4; i += stride) p[i] = make_float4(0.f, 0.f, 0.f, 0.f);
}

// ============================ sort path ============================
// key = (dst>>TSH)<<SRCB_BITS | (src>>SBH)

// S1: per-chunk histogram of keys.
__global__ __launch_bounds__(TPB) void hist_kernel(const int* __restrict__ src,
                                                   const int* __restrict__ dst,
                                                   unsigned* __restrict__ blockhist,
                                                   int E, int per) {
    extern __shared__ unsigned hist[];   // KEYS
    for (int i = threadIdx.x; i < KEYS; i += TPB) hist[i] = 0u;
    __syncthreads();
    int blk = blockIdx.x;
    int e0 = blk * per;              // multiple of 4
    int e1 = min(e0 + per, E);
    const int4* src4 = (const int4*)src;
    const int4* dst4 = (const int4*)dst;
    int g0 = e0 >> 2, g1 = e1 >> 2;
    for (int g = g0 + threadIdx.x; g < g1; g += TPB) {
        int4 s = src4[g];
        int4 d = dst4[g];
        atomicAdd(&hist[((((unsigned)d.x) >> TSH) << SRCB_BITS) | (((unsigned)s.x) >> SBH)], 1u);
        atomicAdd(&hist[((((unsigned)d.y) >> TSH) << SRCB_BITS) | (((unsigned)s.y) >> SBH)], 1u);
        atomicAdd(&hist[((((unsigned)d.z) >> TSH) << SRCB_BITS) | (((unsigned)s.z) >> SBH)], 1u);
        atomicAdd(&hist[((((unsigned)d.w) >> TSH) << SRCB_BITS) | (((unsigned)s.w) >> SBH)], 1u);
    }
    for (int e = (g1 << 2) + threadIdx.x; e < e1; e += TPB)   // tail
        atomicAdd(&hist[((((unsigned)dst[e]) >> TSH) << SRCB_BITS) | (((unsigned)src[e]) >> SBH)], 1u);
    __syncthreads();
    for (int i = threadIdx.x; i < KEYS; i += TPB)
        blockhist[(size_t)blk * KEYS + i] = hist[i];
}

// S2a: per-key column exclusive scan over SBLK chunks (in place); totals[key].
// One wave per key; 3 chunks per thread (64*3 = 192 = SBLK).
__global__ __launch_bounds__(64) void colscan_kernel(unsigned* __restrict__ blockhist,
                                                     unsigned* __restrict__ totals) {
    int key = blockIdx.x;
    int t = threadIdx.x;              // 0..63, single wave
    unsigned v0 = blockhist[(size_t)(3 * t)     * KEYS + key];
    unsigned v1 = blockhist[(size_t)(3 * t + 1) * KEYS + key];
    unsigned v2 = blockhist[(size_t)(3 * t + 2) * KEYS + key];
    unsigned run = v0 + v1 + v2;
    unsigned v = run;
    for (int o = 1; o < 64; o <<= 1) {
        unsigned u = __shfl_up(v, o, 64);
        if (t >= o) v += u;
    }
    unsigned excl = v - run;
    blockhist[(size_t)(3 * t)     * KEYS + key] = excl;
    blockhist[(size_t)(3 * t + 1) * KEYS + key] = excl + v0;
    blockhist[(size_t)(3 * t + 2) * KEYS + key] = excl + v0 + v1;
    if (t == 63) totals[key] = v;
}

// S2b: exclusive scan of KEYS totals -> base[KEYS+1].  16 bins per thread.
__global__ __launch_bounds__(ETPB) void scan_kernel(const unsigned* __restrict__ totals,
                                                    unsigned* __restrict__ base) {
    __shared__ unsigned wpart[ETPB / 64];
    int t = threadIdx.x;
    unsigned run = 0;
    for (int k = 0; k < KEYS / ETPB; ++k) run += totals[t * (KEYS / ETPB) + k];
    unsigned lane = t & 63, wv = t >> 6;
    unsigned v = run;
    for (int o = 1; o < 64; o <<= 1) {
        unsigned u = __shfl_up(v, o, 64);
        if (lane >= (unsigned)o) v += u;
    }
    if (lane == 63) wpart[wv] = v;
    __syncthreads();
    unsigned wbase = 0;
    for (int w = 0; w < (int)(ETPB / 64); ++w) if ((unsigned)w < wv) wbase += wpart[w];
    unsigned e = wbase + v - run;
    for (int k = 0; k < KEYS / ETPB; ++k) {
        base[t * (KEYS / ETPB) + k] = e;
        e += totals[t * (KEYS / ETPB) + k];
    }
    if (t == ETPB - 1) base[KEYS] = e;   // == E
}

// S3: scatter edges into key order.
// record: w0 = src(0:19) | typ(20:23) | doffL8(24:31); w1 = doffH6(0:5) | f16(norm)(16:31)
__global__ __launch_bounds__(TPB) void scatter_kernel(const int* __restrict__ src,
                                                      const int* __restrict__ dst,
                                                      const int* __restrict__ typ,
                                                      const float* __restrict__ norm,
                                                      const unsigned* __restrict__ blockhist,
                                                      const unsigned* __restrict__ base,
                                                      uint2* __restrict__ packed,
                                                      int E, int per) {
    extern __shared__ unsigned cnt[];   // KEYS
    int blk = blockIdx.x;
    for (int i = threadIdx.x; i < KEYS; i += TPB)
        cnt[i] = blockhist[(size_t)blk * KEYS + i] + base[i];
    __syncthreads();
    int e0 = blk * per;
    int e1 = min(e0 + per, E);
    const int4*   src4 = (const int4*)src;
    const int4*   dst4 = (const int4*)dst;
    const int4*   typ4 = (const int4*)typ;
    const float4* nrm4 = (const float4*)norm;
    int g0 = e0 >> 2, g1 = e1 >> 2;

#define PUT(SS, DD, TT, NN)                                                        \
    {                                                                              \
        unsigned _s = (unsigned)(SS);                                              \
        unsigned _d = (unsigned)(DD);                                              \
        unsigned _key = ((_d >> TSH) << SRCB_BITS) | (_s >> SBH);                  \
        unsigned _pos = atomicAdd(&cnt[_key], 1u);                                 \
        unsigned _doff = _d & (TILEN - 1u);                                        \
        unsigned _w0 = _s | (((unsigned)(TT)) << 20) | ((_doff & 0xFFu) << 24);    \
        unsigned _w1 = (_doff >> 8) |                                              \
                       ((unsigned)__half_as_ushort(__float2half_rn(NN)) << 16);    \
        packed[_pos] = make_uint2(_w0, _w1);                                       \
    }

    for (int g = g0 + threadIdx.x; g < g1; g += TPB) {
        int4 s = src4[g];
        int4 d = dst4[g];
        int4 t = typ4[g];
        float4 nm = nrm4[g];
        PUT(s.x, d.x, t.x, nm.x)
        PUT(s.y, d.y, t.y, nm.y)
        PUT(s.z, d.z, t.z, nm.z)
        PUT(s.w, d.w, t.w, nm.w)
    }
    for (int e = (g1 << 2) + threadIdx.x; e < e1; e += TPB)   // tail
        PUT(src[e], dst[e], typ[e], norm[e])
#undef PUT
}

// Edge pass: SPLIT blocks per 16K-node dst tile; block handles 32 consecutive
// src-block runs. Per run: stage the 4096-node src window into LDS (coalesced
// from the L2-resident x array), then process the run's edges with ZERO
// divergent vector-memory ops: coalesced record stream + LDS gather +
// LDS-atomic accumulate. Flush the 128KB accumulator via coalesced global
// atomics into pre-zeroed H.
__global__ __launch_bounds__(ETPB) void edge_tile_kernel(
    const unsigned long long* __restrict__ rec8,  // packed, key order
    const unsigned* __restrict__ base,            // [KEYS+1]
    const __half2* __restrict__ xh,               // gather source [N], 4MB
    const float* __restrict__ Wl,                 // [64] this layer
    float* __restrict__ H,                        // [2N] f32, pre-zeroed
    int N)
{
    extern __shared__ float dsm[];
    float*   acc0 = dsm;                          // TILEN
    float*   acc1 = dsm + TILEN;                  // TILEN
    __half2* xwin = (__half2*)(dsm + 2 * TILEN);  // SRCWIN
    __shared__ float sW[64];

    int t = threadIdx.x;
    for (int i = t; i < TILEN; i += ETPB) { acc0[i] = 0.f; acc1[i] = 0.f; }
    if (t < 64) sW[t] = Wl[t];

    int blk  = blockIdx.x;
    int tile = blk / SPLIT;
    int sl   = blk % SPLIT;
    int k0   = (tile << SRCB_BITS) + sl * RUNS_PER_BLOCK;

    for (int k = k0; k < k0 + RUNS_PER_BLOCK; ++k) {
        unsigned r0 = base[k], r1 = base[k + 1];
        if (r0 == r1) continue;                   // block-uniform -> safe
        unsigned sb = ((unsigned)k & ((1u << SRCB_BITS) - 1u)) << SBH;
        __syncthreads();                          // xwin readers of prev run done
        for (int j = t; j < SRCWIN; j += ETPB) {
            unsigned g = sb + (unsigned)j;
            xwin[j] = (g < (unsigned)N) ? xh[g] : __half2{};
        }
        __syncthreads();
        for (unsigned e = r0 + t; e < r1; e += ETPB) {
            unsigned long long q = __builtin_nontemporal_load(&rec8[e]);
            unsigned w0 = (unsigned)q;
            unsigned w1 = (unsigned)(q >> 32);
            unsigned sloc = (w0 & 0xFFFFFu) & (SRCWIN - 1u);
            int      wb   = (int)((w0 >> 20) & 15u) << 2;
            unsigned doff = (w0 >> 24) | ((w1 & 0x3Fu) << 8);
            float    nm   = __half2float(__ushort_as_half((unsigned short)(w1 >> 16)));
            __half2  hv   = xwin[sloc];
            float x0 = __low2float(hv), x1 = __high2float(hv);
            float m0 = (x0 * sW[wb + 0] + x1 * sW[wb + 2]) * nm;
            float m1 = (x0 * sW[wb + 1] + x1 * sW[wb + 3]) * nm;
            atomicAdd(&acc0[doff], m0);
            atomicAdd(&acc1[doff], m1);
        }
    }
    __syncthreads();

    // coalesced flush into H
    int nodeBase = tile << TSH;
    for (int i = t; i < TILEN; i += ETPB) {
        int node = nodeBase + i;
        if (node < N) {
            atomicAdd(&H[2 * (size_t)node],     acc0[i]);
            atomicAdd(&H[2 * (size_t)node + 1], acc1[i]);
        }
    }
}

// Per-layer epilogue: v = H + bias (+relu)(+skip); half2 store; w_mlp dot
// partial; re-zero H for the next layer.
__global__ __launch_bounds__(TPB) void epilogue_kernel(
    float2* __restrict__ H2,
    const float* __restrict__ bias2,
    const __half2* __restrict__ skiph,    // nullable
    __half2* __restrict__ outh,           // nullable
    const float2* __restrict__ w2,        // nullable
    float* __restrict__ acc,
    int N, int do_relu, int zeroH)
{
    __shared__ float wred[TPB / 64];
    float b0 = bias2[0], b1 = bias2[1];
    int i = blockIdx.x * TPB + threadIdx.x;
    int stride = gridDim.x * TPB;
    float part = 0.f;
    for (; i < N; i += stride) {
        float2 v = H2[i];
        v.x += b0; v.y += b1;
        if (do_relu) { v.x = fmaxf(v.x, 0.f); v.y = fmaxf(v.y, 0.f); }
        if (skiph) { __half2 sv = skiph[i]; v.x += __low2float(sv); v.y += __high2float(sv); }
        if (outh)  outh[i] = __float22half2_rn(make_float2(v.x, v.y));
        if (w2)    { float2 wv = w2[i]; part += v.x * wv.x + v.y * wv.y; }
        if (zeroH) H2[i] = make_float2(0.f, 0.f);
    }
    if (w2) {
        for (int o = 32; o > 0; o >>= 1) part += __shfl_down(part, o, 64);
        if ((threadIdx.x & 63) == 0) wred[threadIdx.x >> 6] = part;
        __syncthreads();
        if (threadIdx.x == 0) {
            float s = 0.f;
            for (int w = 0; w < (int)(TPB / 64); ++w) s += wred[w];
            atomicAdd(acc, s);
        }
    }
}

// ============================ fallback path (round-1, known-good) ============================

__global__ __launch_bounds__(256) void edge_kernel(
    const float* __restrict__ x, const int* __restrict__ src,
    const int* __restrict__ dst, const int* __restrict__ typ,
    const float* __restrict__ norm, const float* __restrict__ Wl,
    float* __restrict__ h, int E)
{
    __shared__ float sW[64];
    if (threadIdx.x < 64) sW[threadIdx.x] = Wl[threadIdx.x];
    __syncthreads();
    const float2* __restrict__ x2 = (const float2*)x;
    int tid = blockIdx.x * blockDim.x + threadIdx.x;
    int stride = gridDim.x * blockDim.x;
    for (int e = tid; e < E; e += stride) {
        int s = src[e], d = dst[e], t = typ[e];
        float nm = norm[e];
        float2 xv = x2[s];
        int wb = t << 2;
        float m0 = (xv.x * sW[wb + 0] + xv.y * sW[wb + 2]) * nm;
        float m1 = (xv.x * sW[wb + 1] + xv.y * sW[wb + 3]) * nm;
        atomicAdd(&h[2 * (size_t)d],     m0);
        atomicAdd(&h[2 * (size_t)d + 1], m1);
    }
}

__global__ void node_kernel(const float* __restrict__ h, const float* __restrict__ bias_l,
                            const float* __restrict__ skip, float* __restrict__ xout,
                            int N, int do_relu)
{
    float b0 = bias_l[0], b1 = bias_l[1];
    const float2* __restrict__ h2 = (const float2*)h;
    const float2* __restrict__ s2 = (const float2*)skip;
    float2* __restrict__ o2 = (float2*)xout;
    int i = blockIdx.x * blockDim.x + threadIdx.x;
    int stride = gridDim.x * blockDim.x;
    for (; i < N; i += stride) {
        float2 v = h2[i];
        v.x += b0; v.y += b1;
        if (do_relu) { v.x = fmaxf(v.x, 0.f); v.y = fmaxf(v.y, 0.f); }
        if (skip) { float2 sv = s2[i]; v.x += sv.x; v.y += sv.y; }
        o2[i] = v;
    }
}

__global__ __launch_bounds__(256) void dot_kernel(const float* __restrict__ a,
                                                  const float* __restrict__ b,
                                                  float* __restrict__ acc, int n)
{
    int i = blockIdx.x * blockDim.x + threadIdx.x;
    int stride = gridDim.x * blockDim.x;
    float s = 0.f;
    int n4 = n >> 2;
    const float4* __restrict__ a4 = (const float4*)a;
    const float4* __restrict__ b4 = (const float4*)b;
    for (int g = i; g < n4; g += stride) {
        float4 av = a4[g], bv = b4[g];
        s += av.x * bv.x + av.y * bv.y + av.z * bv.z + av.w * bv.w;
    }
    for (int e = (n4 << 2) + i; e < n; e += stride) s += a[e] * b[e];
    for (int off = 32; off > 0; off >>= 1) s += __shfl_down(s, off, 64);
    __shared__ float wsum[4];
    int lane = threadIdx.x & 63, wv = threadIdx.x >> 6;
    if (lane == 0) wsum[wv] = s;
    __syncthreads();
    if (threadIdx.x == 0) atomicAdd(acc, wsum[0] + wsum[1] + wsum[2] + wsum[3]);
}

// ============================ launch ============================

static inline size_t align256(size_t x) { return (x + 255) & ~(size_t)255; }

extern "C" void kernel_launch(void* const* d_in, const int* in_sizes, int n_in,
                              void* d_out, int out_size, void* d_ws, size_t ws_size,
                              hipStream_t stream) {
    const float* features = (const float*)d_in[0];   // [N*2]
    const float* norm     = (const float*)d_in[1];   // [E]
    const float* V        = (const float*)d_in[2];   // [L,B,2,2]
    const float* comp     = (const float*)d_in[3];   // [L,R,B]
    const float* bias     = (const float*)d_in[4];   // [L,2]
    const float* w_mlp    = (const float*)d_in[5];   // [N*2]
    const float* b_mlp    = (const float*)d_in[6];   // [1]
    const int*   esrc     = (const int*)d_in[7];
    const int*   edst     = (const int*)d_in[8];
    const int*   etyp     = (const int*)d_in[9];

    int NH = in_sizes[0];
    int N  = NH / 2;
    int E  = in_sizes[7];

    char* ws = (char*)d_ws;
    size_t oW    = 0;                                        // [256] f32
    size_t oAcc  = align256(oW + 1024);
    size_t oBase = align256(oAcc + 4);                       // u32 [KEYS+1]
    size_t oTot  = align256(oBase + (size_t)(KEYS + 1) * 4); // u32 [KEYS]
    size_t oFH   = align256(oTot + (size_t)KEYS * 4);        // half2 features [N]
    size_t oAH   = align256(oFH + (size_t)N * 4);
    size_t oBH   = align256(oAH + (size_t)N * 4);
    size_t oCH   = align256(oBH + (size_t)N * 4);
    size_t oH    = align256(oCH + (size_t)N * 4);            // f32 [2N] = 8MB
    size_t oHist = align256(oH + (size_t)NH * 4);            // u32 [SBLK*KEYS] = 12MB
    size_t oPack = align256(oHist + (size_t)SBLK * KEYS * 4);// uint2 [E] = 128MB
    size_t REQ   = oPack + (size_t)E * 8;                    // ~165MB

    // fallback f32 scratch overlays the sort-path big arrays
    float* A = (float*)(ws + oFH);      // 8MB: spans FH+AH
    float* B = (float*)(ws + oBH);      // 8MB: spans BH+CH
    float* C = (float*)(ws + oPack);    // 8MB: start of pack region

    float* W   = (float*)(ws + oW);
    float* acc = (float*)(ws + oAcc);

    prep_kernel<<<1, 256, 0, stream>>>(V, comp, W, acc);

    if (ws_size >= REQ && N <= (1 << 20)) {
        __half2* FH = (__half2*)(ws + oFH);
        __half2* AH = (__half2*)(ws + oAH);
        __half2* BH = (__half2*)(ws + oBH);
        __half2* CH = (__half2*)(ws + oCH);
        float*   Hb = (float*)(ws + oH);
        unsigned* base      = (unsigned*)(ws + oBase);
        unsigned* totals    = (unsigned*)(ws + oTot);
        unsigned* blockhist = (unsigned*)(ws + oHist);
        uint2*    packed    = (uint2*)(ws + oPack);
        unsigned long long* packed8 = (unsigned long long*)packed;

        int per = (((E + SBLK - 1) / SBLK) + 3) & ~3;   // multiple of 4
        int ntiles = (N + TILEN - 1) / TILEN;           // 62 for N=1M
        int egrid  = ntiles * SPLIT;                    // 496

        static bool attr_done = false;
        if (!attr_done) {
            (void)hipFuncSetAttribute((const void*)hist_kernel,
                                      hipFuncAttributeMaxDynamicSharedMemorySize,
                                      KEYS_LDS_BYTES);
            (void)hipFuncSetAttribute((const void*)scatter_kernel,
                                      hipFuncAttributeMaxDynamicSharedMemorySize,
                                      KEYS_LDS_BYTES);
            (void)hipFuncSetAttribute((const void*)edge_tile_kernel,
                                      hipFuncAttributeMaxDynamicSharedMemorySize,
                                      EDGE_LDS_BYTES);
            attr_done = true;
        }

        int cb  = min((N + TPB - 1) / TPB, 2048);
        int nb2 = min((N + TPB - 1) / TPB, 2048);
        f2h_kernel    <<<cb,   TPB, 0, stream>>>((const float2*)features, FH, N);
        zero_kernel   <<<(NH / 4 + 255) / 256, 256, 0, stream>>>((float4*)Hb, NH / 4);
        hist_kernel   <<<SBLK, TPB, KEYS_LDS_BYTES, stream>>>(esrc, edst, blockhist, E, per);
        colscan_kernel<<<KEYS, 64,  0, stream>>>(blockhist, totals);
        scan_kernel   <<<1,    ETPB, 0, stream>>>(totals, base);
        scatter_kernel<<<SBLK, TPB, KEYS_LDS_BYTES, stream>>>(
            esrc, edst, etyp, norm, blockhist, base, packed, E, per);

        const float2* w2 = (const float2*)w_mlp;

        // L0: AH = relu(h0 + b0)
        edge_tile_kernel<<<egrid, ETPB, EDGE_LDS_BYTES, stream>>>(packed8, base, FH, W + 0, Hb, N);
        epilogue_kernel <<<nb2,   TPB, 0, stream>>>((float2*)Hb, bias + 0,
            nullptr, AH, nullptr, acc, N, 1, 1);
        // L1: BH = relu(h1 + b1) + features
        edge_tile_kernel<<<egrid, ETPB, EDGE_LDS_BYTES, stream>>>(packed8, base, AH, W + 64, Hb, N);
        epilogue_kernel <<<nb2,   TPB, 0, stream>>>((float2*)Hb, bias + 2,
            FH, BH, nullptr, acc, N, 1, 1);
        // L2: CH = relu(h2 + b2)
        edge_tile_kernel<<<egrid, ETPB, EDGE_LDS_BYTES, stream>>>(packed8, base, BH, W + 128, Hb, N);
        epilogue_kernel <<<nb2,   TPB, 0, stream>>>((float2*)Hb, bias + 4,
            nullptr, CH, nullptr, acc, N, 1, 1);
        // L3: x4 = (h3 + b3) + B, fused dot with w_mlp (x4 not stored)
        edge_tile_kernel<<<egrid, ETPB, EDGE_LDS_BYTES, stream>>>(packed8, base, CH, W + 192, Hb, N);
        epilogue_kernel <<<nb2,   TPB, 0, stream>>>((float2*)Hb, bias + 6,
            BH, nullptr, w2, acc, N, 0, 0);
    } else {
        // fallback: round-1 atomic path (f32 throughout)
        int zb = (NH / 4 + 255) / 256;
        int eb = (E / 4 + 255) / 256;
        int nb = (N + 255) / 256;
        int db = (NH / 4 + 255) / 256;

        zero_kernel<<<zb, 256, 0, stream>>>((float4*)A, NH / 4);
        edge_kernel<<<eb, 256, 0, stream>>>(features, esrc, edst, etyp, norm, W + 0, A, E);
        node_kernel<<<nb, 256, 0, stream>>>(A, bias + 0, nullptr, A, N, 1);

        zero_kernel<<<zb, 256, 0, stream>>>((float4*)B, NH / 4);
        edge_kernel<<<eb, 256, 0, stream>>>(A, esrc, edst, etyp, norm, W + 64, B, E);
        node_kernel<<<nb, 256, 0, stream>>>(B, bias + 2, features, B, N, 1);

        zero_kernel<<<zb, 256, 0, stream>>>((float4*)C, NH / 4);
        edge_kernel<<<eb, 256, 0, stream>>>(B, esrc, edst, etyp, norm, W + 128, C, E);
        node_kernel<<<nb, 256, 0, stream>>>(C, bias + 4, nullptr, C, N, 1);

        zero_kernel<<<zb, 256, 0, stream>>>((float4*)A, NH / 4);
        edge_kernel<<<eb, 256, 0, stream>>>(C, esrc, edst, etyp, norm, W + 192, A, E);
        node_kernel<<<nb, 256, 0, stream>>>(A, bias + 6, B, A, N, 0);

        dot_kernel<<<db, 256, 0, stream>>>(A, w_mlp, acc, NH);
    }

    finalize_kernel<<<1, 1, 0, stream>>>(acc, b_mlp, (float*)d_out);
}